// Round 2
// baseline (112.727 us; speedup 1.0000x reference)
//
#include <hip/hip_runtime.h>

#define NODES 512
#define WORDS 16          // 512 bits / 32
#define NBATCH 32
#define SENTINEL 11       // MAX_DISTANCE + 1
#define NEMB 12           // MAX_DISTANCE + 2
#define NOUT 8

// ---------------------------------------------------------------------------
// Kernel A: pack adjacency bits. One thread per element of A (B*N*N total).
// bit(b,i,j) = (A[b,i,j] > 0.5) && mask[b,i] && mask[b,j]
// Wave-wide __ballot (64-bit on gfx950) packs 64 bits -> 2 u32 words.
// node_mask is a bool jax array uploaded as int32 (harness: integer -> int*).
// ---------------------------------------------------------------------------
__global__ void __launch_bounds__(256)
pack_bits(const float* __restrict__ A, const int* __restrict__ mask,
          unsigned int* __restrict__ bitA) {
    size_t tid = (size_t)blockIdx.x * 256 + threadIdx.x;   // grid sized exactly
    int j = (int)(tid & 511);
    int i = (int)((tid >> 9) & 511);
    int b = (int)(tid >> 18);
    float a = A[tid];
    bool bit = (a > 0.5f) && (mask[b * NODES + i] != 0) && (mask[b * NODES + j] != 0);
    unsigned long long bal = __ballot(bit);
    if ((threadIdx.x & 63) == 0) {
        size_t w = tid >> 5;                   // even for lane 0
        bitA[w]     = (unsigned int)bal;
        bitA[w + 1] = (unsigned int)(bal >> 32);
    }
}

// ---------------------------------------------------------------------------
// Kernel B: symmetrize: adj[b,i,w] = bitA[b,i,w] | bits of column i over rows
// 32w..32w+31. One thread per (b,i,w) word.
// ---------------------------------------------------------------------------
__global__ void __launch_bounds__(256)
symmetrize(const unsigned int* __restrict__ bitA, unsigned int* __restrict__ adjb) {
    int tid = blockIdx.x * 256 + threadIdx.x;   // total B*N*WORDS = 262144
    int w = tid & 15;
    int i = (tid >> 4) & 511;
    int b = tid >> 13;
    const unsigned int* base = bitA + (size_t)b * NODES * WORDS;
    unsigned int word = base[i * WORDS + w];
    unsigned int t = 0;
    int iw = i >> 5, ib = i & 31;
#pragma unroll
    for (int k = 0; k < 32; ++k) {
        t |= ((base[(32 * w + k) * WORDS + iw] >> ib) & 1u) << k;
    }
    adjb[tid] = word | t;
}

// ---------------------------------------------------------------------------
// Kernel C: per-source BFS + embedding gather.
// Block (i = blockIdx.x source node, b = blockIdx.y batch), 512 threads.
// Thread j keeps symmetric adjacency row j in 16 VGPRs.
// Frontier bitset (16 u32) lives in LDS; rebuilt each hop via per-wave ballot.
// Early exit via __syncthreads_or when no node is newly reached.
// ---------------------------------------------------------------------------
__global__ void __launch_bounds__(512)
bfs_gather(const unsigned int* __restrict__ adjb, const int* __restrict__ mask,
           const float* __restrict__ emb, float* __restrict__ out) {
    const int i = blockIdx.x;
    const int b = blockIdx.y;
    const int j = threadIdx.x;

    __shared__ unsigned int s_frontier[WORDS];
    __shared__ __align__(16) float s_emb[NEMB * NOUT];

    if (j < NEMB * NOUT) s_emb[j] = emb[j];

    // load adjacency row j (64 B, 4x uint4)
    const uint4* rowp = (const uint4*)(adjb + (size_t)(b * NODES + j) * WORDS);
    unsigned int adjrow[WORDS];
    uint4 r0 = rowp[0], r1 = rowp[1], r2 = rowp[2], r3 = rowp[3];
    adjrow[0] = r0.x; adjrow[1] = r0.y; adjrow[2]  = r0.z; adjrow[3]  = r0.w;
    adjrow[4] = r1.x; adjrow[5] = r1.y; adjrow[6]  = r1.z; adjrow[7]  = r1.w;
    adjrow[8] = r2.x; adjrow[9] = r2.y; adjrow[10] = r2.z; adjrow[11] = r2.w;
    adjrow[12] = r3.x; adjrow[13] = r3.y; adjrow[14] = r3.z; adjrow[15] = r3.w;

    const bool valid_i = (mask[b * NODES + i] != 0);
    if (j < WORDS) s_frontier[j] = (valid_i && (i >> 5) == j) ? (1u << (i & 31)) : 0u;

    bool reach = (j == i) && valid_i;
    int dist = reach ? 0 : SENTINEL;
    __syncthreads();

    for (int t = 1; t <= 10; ++t) {
        bool newly = false;
        if (!reach) {
            unsigned int hit = 0;
#pragma unroll
            for (int w = 0; w < WORDS; ++w) hit |= adjrow[w] & s_frontier[w];
            newly = (hit != 0);
        }
        // barrier: everyone done reading s_frontier; also reduces the flag
        int any = __syncthreads_or(newly ? 1 : 0);
        if (newly) { reach = true; dist = t; }
        unsigned long long bal = __ballot(newly);
        if ((j & 63) == 0) {
            int wv = j >> 6;
            s_frontier[2 * wv]     = (unsigned int)bal;
            s_frontier[2 * wv + 1] = (unsigned int)(bal >> 32);
        }
        __syncthreads();
        if (!any) break;
    }

    // out[b,i,j,0:8] = emb[dist,:]   (two coalesced float4 stores)
    const float4* e4 = (const float4*)s_emb;
    float4 lo = e4[dist * 2];
    float4 hi = e4[dist * 2 + 1];
    float4* o = (float4*)(out + ((size_t)(b * NODES + i) * NODES + j) * NOUT);
    o[0] = lo;
    o[1] = hi;
}

// ---------------------------------------------------------------------------
extern "C" void kernel_launch(void* const* d_in, const int* in_sizes, int n_in,
                              void* d_out, int out_size, void* d_ws, size_t ws_size,
                              hipStream_t stream) {
    const float* adjacency = (const float*)d_in[0];
    const int* node_mask = (const int*)d_in[1];   // bool -> int32 on upload
    const float* emb = (const float*)d_in[2];
    float* out = (float*)d_out;

    unsigned int* bitA = (unsigned int*)d_ws;                       // 1 MB
    unsigned int* adjb = bitA + (size_t)NBATCH * NODES * WORDS;     // 1 MB

    // A: 32*512*512 = 8388608 elements, 256 threads/block -> 32768 blocks
    pack_bits<<<32768, 256, 0, stream>>>(adjacency, node_mask, bitA);
    // B: 32*512*16 = 262144 words -> 1024 blocks
    symmetrize<<<1024, 256, 0, stream>>>(bitA, adjb);
    // C: one block per (source, batch)
    bfs_gather<<<dim3(NODES, NBATCH), 512, 0, stream>>>(adjb, node_mask, emb, out);
}